// Round 1
// 578.949 us; speedup vs baseline: 1.1939x; 1.1939x over previous
//
#include <hip/hip_runtime.h>
#include <math.h>

#define NN 100000
#define NE 3200000

constexpr int BLK = 256;
constexpr int GRID_EDGE = 2048;

typedef float f4 __attribute__((ext_vector_type(4)));
typedef _Float16 h4 __attribute__((ext_vector_type(4)));
typedef _Float16 h8 __attribute__((ext_vector_type(8)));

// ws layout (bytes):
//   [0,128)        stats: sum[16], sumsq[16]   (memset to 0 each launch)
//   [128,256)      scale[16], shift[16]
//   [1024, +3.2MB) p1h : NN rows x 16 half (32B/row)
//   [...,  +3.2MB) p2h
//   [..., +102.4MB) eh : NE rows x 16 half    (optional, if ws is big enough)

__device__ __forceinline__ void matvec16_acc(const float* __restrict__ sW,
                                             const float v[16], float acc[16]) {
  // acc[j] += sum_k v[k] * W[j][k]   (W row-major 16x16 in LDS, wave-uniform reads)
#pragma unroll
  for (int j = 0; j < 16; ++j) {
    float a = acc[j];
#pragma unroll
    for (int q = 0; q < 4; ++q) {
      float4 w = ((const float4*)(sW + j * 16))[q];
      a = fmaf(v[q * 4 + 0], w.x, a);
      a = fmaf(v[q * 4 + 1], w.y, a);
      a = fmaf(v[q * 4 + 2], w.z, a);
      a = fmaf(v[q * 4 + 3], w.w, a);
    }
    acc[j] = a;
  }
}

__device__ __forceinline__ void load_row16(const float* __restrict__ base,
                                           size_t row, float v[16]) {
  const f4* r = (const f4*)(base + row * 16);
#pragma unroll
  for (int q = 0; q < 4; ++q) {
    f4 t = r[q];
    v[q * 4 + 0] = t[0]; v[q * 4 + 1] = t[1];
    v[q * 4 + 2] = t[2]; v[q * 4 + 3] = t[3];
  }
}

__device__ __forceinline__ void load_row16_nt(const float* __restrict__ base,
                                              size_t row, float v[16]) {
  const f4* r = (const f4*)(base + row * 16);
#pragma unroll
  for (int q = 0; q < 4; ++q) {
    f4 t = __builtin_nontemporal_load(r + q);
    v[q * 4 + 0] = t[0]; v[q * 4 + 1] = t[1];
    v[q * 4 + 2] = t[2]; v[q * 4 + 3] = t[3];
  }
}

__device__ __forceinline__ h8 pack_h8(const float* v) {
  h8 o;
#pragma unroll
  for (int i = 0; i < 8; ++i) o[i] = (_Float16)v[i];
  return o;
}

__global__ __launch_bounds__(BLK)
void node_proj(const float* __restrict__ x, const float* __restrict__ W1,
               const float* __restrict__ W2, h8* __restrict__ p1h,
               h8* __restrict__ p2h) {
  __shared__ __align__(16) float sW1[256];
  __shared__ __align__(16) float sW2[256];
  for (int i = threadIdx.x; i < 256; i += BLK) { sW1[i] = W1[i]; sW2[i] = W2[i]; }
  __syncthreads();
  int n = blockIdx.x * BLK + threadIdx.x;
  if (n >= NN) return;
  float xv[16];
  load_row16(x, (size_t)n, xv);
  float y1[16], y2[16];
#pragma unroll
  for (int j = 0; j < 16; ++j) { y1[j] = 0.f; y2[j] = 0.f; }
  matvec16_acc(sW1, xv, y1);
  matvec16_acc(sW2, xv, y2);
  // regular (cached) stores: pass1 reads these from L2 immediately after
  p1h[(size_t)n * 2 + 0] = pack_h8(y1);
  p1h[(size_t)n * 2 + 1] = pack_h8(y1 + 8);
  p2h[(size_t)n * 2 + 0] = pack_h8(y2);
  p2h[(size_t)n * 2 + 1] = pack_h8(y2 + 8);
}

// Pass 1: compute e = ea@W0.T + p1[s] + p2[d]; accumulate per-channel sum/sumsq;
// stash e (fp16 in ws if EH, else fp32 into out) so pass 2 never gathers.
// TABS=false fallback recomputes node projections from x (no ws tables).
template <bool TABS, bool EH>
__global__ __launch_bounds__(BLK)
void edge_pass1(const float* __restrict__ ea, const int* __restrict__ ei,
                const float* __restrict__ xO, const h8* __restrict__ p1h,
                const h8* __restrict__ p2h, const float* __restrict__ W0g,
                const float* __restrict__ W1g, const float* __restrict__ W2g,
                float* __restrict__ stats, _Float16* __restrict__ eh,
                float* __restrict__ out) {
  __shared__ __align__(16) float sW0[256];
  __shared__ __align__(16) float sW1[256];
  __shared__ __align__(16) float sW2[256];
  __shared__ float red[4][32];
  for (int i = threadIdx.x; i < 256; i += BLK) {
    sW0[i] = W0g[i];
    if (!TABS) { sW1[i] = W1g[i]; sW2[i] = W2g[i]; }
  }
  __syncthreads();

  float sum[16], ssq[16];
#pragma unroll
  for (int j = 0; j < 16; ++j) { sum[j] = 0.f; ssq[j] = 0.f; }

  const int total = gridDim.x * BLK;
  for (int e = blockIdx.x * BLK + threadIdx.x; e < NE; e += total) {
    int s = __builtin_nontemporal_load(ei + e);
    int d = __builtin_nontemporal_load(ei + NE + e);
    float eav[16];
    load_row16_nt(ea, (size_t)e, eav);
    float ev[16];
    if (TABS) {
      // gathers: regular loads — we WANT these cached in L2
      h8 a0 = p1h[(size_t)s * 2 + 0];
      h8 a1 = p1h[(size_t)s * 2 + 1];
      h8 b0 = p2h[(size_t)d * 2 + 0];
      h8 b1 = p2h[(size_t)d * 2 + 1];
#pragma unroll
      for (int j = 0; j < 8; ++j) {
        ev[j]     = (float)a0[j] + (float)b0[j];
        ev[8 + j] = (float)a1[j] + (float)b1[j];
      }
      matvec16_acc(sW0, eav, ev);
    } else {
      float xs[16], xd[16];
      load_row16(xO, (size_t)s, xs);
      load_row16(xO, (size_t)d, xd);
#pragma unroll
      for (int j = 0; j < 16; ++j) ev[j] = 0.f;
      matvec16_acc(sW0, eav, ev);
      matvec16_acc(sW1, xs, ev);
      matvec16_acc(sW2, xd, ev);
    }
#pragma unroll
    for (int j = 0; j < 16; ++j) {
      sum[j] += ev[j];
      ssq[j] = fmaf(ev[j], ev[j], ssq[j]);
    }
    if (EH) {
      h8* ep = (h8*)(eh + (size_t)e * 16);
      __builtin_nontemporal_store(pack_h8(ev), ep);
      __builtin_nontemporal_store(pack_h8(ev + 8), ep + 1);
    } else {
      f4* orow = (f4*)(out + (size_t)e * 16);
#pragma unroll
      for (int q = 0; q < 4; ++q) {
        f4 o;
        o[0] = ev[q * 4 + 0]; o[1] = ev[q * 4 + 1];
        o[2] = ev[q * 4 + 2]; o[3] = ev[q * 4 + 3];
        __builtin_nontemporal_store(o, orow + q);
      }
    }
  }

#pragma unroll
  for (int off = 32; off > 0; off >>= 1) {
#pragma unroll
    for (int j = 0; j < 16; ++j) {
      sum[j] += __shfl_down(sum[j], off);
      ssq[j] += __shfl_down(ssq[j], off);
    }
  }
  int wid = threadIdx.x >> 6;
  int lane = threadIdx.x & 63;
  if (lane == 0) {
#pragma unroll
    for (int j = 0; j < 16; ++j) {
      red[wid][j] = sum[j];
      red[wid][16 + j] = ssq[j];
    }
  }
  __syncthreads();
  if (threadIdx.x < 32) {
    float v = red[0][threadIdx.x] + red[1][threadIdx.x] +
              red[2][threadIdx.x] + red[3][threadIdx.x];
    atomicAdd(stats + threadIdx.x, v);
  }
}

__global__ void finalize_kernel(const float* __restrict__ stats,
                                const float* __restrict__ gamma,
                                const float* __restrict__ beta,
                                float* __restrict__ ss) {
  int j = threadIdx.x;
  if (j < 16) {
    const float inv_n = 1.0f / (float)NE;
    float mean = stats[j] * inv_n;
    float var = fmaf(-mean, mean, stats[16 + j] * inv_n);
    float sc = gamma[j] / sqrtf(var + 1e-5f);
    ss[j] = sc;
    ss[16 + j] = fmaf(-mean, sc, beta[j]);
  }
}

// Pass 2: pure coalesced streaming — no gathers, no matvec.
// Flat float4-granular mapping: i in [0, NE*4); q = i&3 is constant per thread
// (stride is a multiple of 4), so scale/shift live in 8 registers.
template <bool EH>
__global__ __launch_bounds__(BLK)
void edge_pass2(const float* __restrict__ ea, const _Float16* __restrict__ eh,
                const float* __restrict__ ssg, float* __restrict__ out) {
  __shared__ float sSS[32];
  if (threadIdx.x < 32) sSS[threadIdx.x] = ssg[threadIdx.x];
  __syncthreads();
  const int totalv = NE * 4;
  const int stride = gridDim.x * BLK;
  int i0 = blockIdx.x * BLK + threadIdx.x;
  int c = (i0 & 3) * 4;
  float sc0 = sSS[c + 0], sc1 = sSS[c + 1], sc2 = sSS[c + 2], sc3 = sSS[c + 3];
  float sh0 = sSS[16 + c + 0], sh1 = sSS[16 + c + 1];
  float sh2 = sSS[16 + c + 2], sh3 = sSS[16 + c + 3];
  for (int i = i0; i < totalv; i += stride) {
    f4 av = __builtin_nontemporal_load((const f4*)ea + i);
    f4 evv;
    if (EH) {
      h4 hv = __builtin_nontemporal_load((const h4*)eh + i);
      evv[0] = (float)hv[0]; evv[1] = (float)hv[1];
      evv[2] = (float)hv[2]; evv[3] = (float)hv[3];
    } else {
      evv = __builtin_nontemporal_load((const f4*)out + i);
    }
    f4 o;
    o[0] = av[0] + fmaxf(0.f, fmaf(evv[0], sc0, sh0));
    o[1] = av[1] + fmaxf(0.f, fmaf(evv[1], sc1, sh1));
    o[2] = av[2] + fmaxf(0.f, fmaf(evv[2], sc2, sh2));
    o[3] = av[3] + fmaxf(0.f, fmaf(evv[3], sc3, sh3));
    __builtin_nontemporal_store(o, (f4*)out + i);
  }
}

extern "C" void kernel_launch(void* const* d_in, const int* in_sizes, int n_in,
                              void* d_out, int out_size, void* d_ws, size_t ws_size,
                              hipStream_t stream) {
  const float* x     = (const float*)d_in[0];
  const int*   ei    = (const int*)d_in[1];
  const float* ea    = (const float*)d_in[2];
  const float* W0    = (const float*)d_in[3];
  const float* W1    = (const float*)d_in[5];
  const float* W2    = (const float*)d_in[7];
  const float* gamma = (const float*)d_in[9];
  const float* beta  = (const float*)d_in[10];
  float* out = (float*)d_out;

  float* ws    = (float*)d_ws;
  float* stats = ws;            // 32 floats @ byte 0
  float* ss    = ws + 32;       // 32 floats @ byte 128
  h8* p1h = (h8*)((char*)d_ws + 1024);
  h8* p2h = p1h + (size_t)NN * 2;
  _Float16* eh = (_Float16*)(p2h + (size_t)NN * 2);

  size_t need_tabs = 1024 + (size_t)NN * 64;              // ~6.4 MB
  size_t need_eh   = need_tabs + (size_t)NE * 32;         // ~108.8 MB
  bool has_tabs = ws_size >= need_tabs;
  bool has_eh   = ws_size >= need_eh;

  hipMemsetAsync(stats, 0, 32 * sizeof(float), stream);

  if (has_tabs) {
    node_proj<<<(NN + BLK - 1) / BLK, BLK, 0, stream>>>(x, W1, W2, p1h, p2h);
    if (has_eh)
      edge_pass1<true, true><<<GRID_EDGE, BLK, 0, stream>>>(
          ea, ei, x, p1h, p2h, W0, W1, W2, stats, eh, out);
    else
      edge_pass1<true, false><<<GRID_EDGE, BLK, 0, stream>>>(
          ea, ei, x, p1h, p2h, W0, W1, W2, stats, eh, out);
  } else {
    edge_pass1<false, false><<<GRID_EDGE, BLK, 0, stream>>>(
        ea, ei, x, p1h, p2h, W0, W1, W2, stats, eh, out);
  }

  finalize_kernel<<<1, 64, 0, stream>>>(stats, gamma, beta, ss);

  if (has_eh)
    edge_pass2<true><<<GRID_EDGE, BLK, 0, stream>>>(ea, eh, ss, out);
  else
    edge_pass2<false><<<GRID_EDGE, BLK, 0, stream>>>(ea, eh, ss, out);
}